// Round 3
// baseline (51.284 us; speedup 1.0000x reference)
//
#include <hip/hip_runtime.h>
#include <hip/hip_bf16.h>

typedef __attribute__((ext_vector_type(8))) short short8;
typedef __attribute__((ext_vector_type(4))) float f32x4;

#define MFMA(a, b, c) __builtin_amdgcn_mfma_f32_16x16x32_bf16((a), (b), (c), 0, 0, 0)

__device__ __forceinline__ unsigned short f2bf(float f) {
  union { float f; unsigned int u; } v; v.f = f;
  unsigned int u = v.u;
  unsigned int r = u + 0x7FFFu + ((u >> 16) & 1u);  // RNE
  return (unsigned short)(r >> 16);
}

// packed pair: low 16 = bf16(a), high 16 = bf16(b); compiler -> v_cvt_pk_bf16_f32
__device__ __forceinline__ unsigned int f2bf2(float a, float b) {
  __hip_bfloat162 h2 = __float22bfloat162_rn(make_float2(a, b));
  union { __hip_bfloat162 h; unsigned int u; } cv; cv.h = h2;
  return cv.u;
}

// ---------------------------------------------------------------------------
// k0: W -> W3t bf16 [192 n][384 k] (transposed). blockIdx = k, thread = n.
// ---------------------------------------------------------------------------
__global__ void wconv_kernel(const float* __restrict__ Wq, const float* __restrict__ Wk,
                             const float* __restrict__ Wv, unsigned short* __restrict__ W3t) {
  int k = blockIdx.x;   // 0..383
  int n = threadIdx.x;  // 0..191
  const float* src = (n < 64) ? Wq : ((n < 128) ? Wk : Wv);
  W3t[n * 384 + k] = f2bf(src[k * 64 + (n & 63)]);
}

// ---------------------------------------------------------------------------
// Fused per-batch kernel. 512 threads = 8 waves.
// Dynamic LDS 117,760 B (58,880 ush):
//   attn-phase:  Ql [256][72] @0   | Kl [256][72] @18432 | Vl [64][264] @36864
//                Pb 8x[16][40] @53760
//   proj-phase:  stage buf0 @0 (xl 10240 + wl 7680), buf1 @17920 (same)
//                (overlays Ql/Kl -- those are written only in the epilogue)
// ---------------------------------------------------------------------------
__global__ __launch_bounds__(512, 2) void fused_kernel(
    const float* __restrict__ x, const unsigned short* __restrict__ W3t,
    float* __restrict__ out) {
  extern __shared__ unsigned short sm[];
  unsigned short* Ql = sm;
  unsigned short* Kl = sm + 18432;
  unsigned short* Vl = sm + 36864;

  const int tid = threadIdx.x;  // 0..511
  const int w = tid >> 6, lane = tid & 63, g = lane >> 4, q = lane & 15;
  const int b = blockIdx.x;
  const float* xb = x + (long)b * 256 * 384;

  f32x4 acc[2][12];
  const f32x4 zf = {0.f, 0.f, 0.f, 0.f};
#pragma unroll
  for (int i = 0; i < 2; ++i)
#pragma unroll
    for (int j = 0; j < 12; ++j) acc[i][j] = zf;

  // ---- staging machinery: 2 register sets, 2 LDS buffers ----
  float4 xr[2][4];  // x tile: i = tid + it*512 -> row i>>3, col4 (i&7)*4
  uint4 wr[2][2];   // W3t tile: chunk c = tid + it*512 (<768) -> n=c>>2, koff=(c&3)*8

  auto LOAD = [&](int set, int k0) {
#pragma unroll
    for (int it = 0; it < 4; ++it) {
      int i = tid + it * 512;
      xr[set][it] = *(const float4*)&xb[(i >> 3) * 384 + k0 + (i & 7) * 4];
    }
#pragma unroll
    for (int it = 0; it < 2; ++it) {
      int c = tid + it * 512;
      if (c < 768) {
        int n = c >> 2, koff = (c & 3) * 8;
        wr[set][it] = *(const uint4*)&W3t[n * 384 + k0 + koff];
      }
    }
  };
  auto WRITE = [&](int set, int bufofs) {
#pragma unroll
    for (int it = 0; it < 4; ++it) {
      int i = tid + it * 512;
      int r = i >> 3, c4 = (i & 7) * 4;
      uint2 pk;
      pk.x = f2bf2(xr[set][it].x, xr[set][it].y);
      pk.y = f2bf2(xr[set][it].z, xr[set][it].w);
      *(uint2*)&sm[bufofs + r * 40 + c4] = pk;
    }
#pragma unroll
    for (int it = 0; it < 2; ++it) {
      int c = tid + it * 512;
      if (c < 768) {
        int n = c >> 2, koff = (c & 3) * 8;
        *(uint4*)&sm[bufofs + 10240 + n * 40 + koff] = wr[set][it];
      }
    }
  };
  auto STEP = [&](int bufofs) {
    const unsigned short* xlb = sm + bufofs;
    const unsigned short* wlb = sm + bufofs + 10240;
    short8 a0 = *(const short8*)&xlb[(32 * w + q) * 40 + g * 8];
    short8 a1 = *(const short8*)&xlb[(32 * w + 16 + q) * 40 + g * 8];
#pragma unroll
    for (int ct = 0; ct < 12; ++ct) {
      short8 bfr = *(const short8*)&wlb[(16 * ct + q) * 40 + g * 8];
      acc[0][ct] = MFMA(a0, bfr, acc[0][ct]);
      acc[1][ct] = MFMA(a1, bfr, acc[1][ct]);
    }
  };

  // ---- prologue: D0,D1 in flight; write D0; D2 in flight ----
  LOAD(0, 0);
  LOAD(1, 32);
  WRITE(0, 0);     // waits on set0 loads only (compiler-counted vmcnt)
  LOAD(0, 64);
  __syncthreads();

  // ---- main loop: 1 barrier/step, loads 2 steps deep ----
#pragma unroll
  for (int i = 0; i < 12; ++i) {
    STEP((i & 1) ? 17920 : 0);
    if (i < 11) WRITE((i + 1) & 1, ((i + 1) & 1) ? 17920 : 0);
    if (i < 9)  LOAD((i + 1) & 1, 32 * (i + 3));
    __syncthreads();
  }

  // ---- proj epilogue: QKV -> LDS (D layout: col=lane&15, row=4g+reg) ----
#pragma unroll
  for (int rt = 0; rt < 2; ++rt) {
    const int mb = 32 * w + 16 * rt + 4 * g;  // within-batch row
#pragma unroll
    for (int ct = 0; ct < 12; ++ct) {
      int c = 16 * ct + q;
      unsigned int p01 = f2bf2(acc[rt][ct][0], acc[rt][ct][1]);
      unsigned int p23 = f2bf2(acc[rt][ct][2], acc[rt][ct][3]);
      unsigned short h0 = (unsigned short)p01, h1 = (unsigned short)(p01 >> 16);
      unsigned short h2 = (unsigned short)p23, h3 = (unsigned short)(p23 >> 16);
      if (ct < 4) {
        Ql[(mb + 0) * 72 + c] = h0; Ql[(mb + 1) * 72 + c] = h1;
        Ql[(mb + 2) * 72 + c] = h2; Ql[(mb + 3) * 72 + c] = h3;
      } else if (ct < 8) {
        int cc = c - 64;
        Kl[(mb + 0) * 72 + cc] = h0; Kl[(mb + 1) * 72 + cc] = h1;
        Kl[(mb + 2) * 72 + cc] = h2; Kl[(mb + 3) * 72 + cc] = h3;
      } else {
        int hh = c - 128;
        uint2 pk; pk.x = p01; pk.y = p23;
        *(uint2*)&Vl[hh * 264 + mb] = pk;  // V^T[h][tok..tok+3]
      }
    }
  }
  __syncthreads();

  // ---- attention phase: wave w owns row-tiles {w, 15-w} (17 units each) ----
  unsigned short* Pb = sm + 53760 + w * 640;  // per-wave [16][40] transpose buf
  const float SCL = 0.125f * 1.4426950408889634f;  // H^-0.5 * log2(e), exp->exp2
  const int tt[2] = {w, 15 - w};
#pragma unroll
  for (int ti = 0; ti < 2; ++ti) {
    const int t = tt[ti];
    short8 aq0 = *(const short8*)&Ql[(16 * t + q) * 72 + g * 8];
    short8 aq1 = *(const short8*)&Ql[(16 * t + q) * 72 + 32 + g * 8];

    f32x4 s[16];  // compile-time indexed only -> VGPRs
#pragma unroll
    for (int j = 0; j < 16; ++j) {
      if (j <= t) {
        short8 bk0 = *(const short8*)&Kl[(16 * j + q) * 72 + g * 8];
        short8 bk1 = *(const short8*)&Kl[(16 * j + q) * 72 + 32 + g * 8];
        f32x4 sv = MFMA(aq0, bk0, zf);
        sv = MFMA(aq1, bk1, sv);
#pragma unroll
        for (int jr = 0; jr < 4; ++jr) {
          float v = sv[jr] * SCL;
          if (j == t && q > 4 * g + jr) v = -1e30f;  // causal (diagonal tile)
          sv[jr] = v;
        }
        s[j] = sv;
      }
    }

    // softmax (log2 domain): row r = 16t+4g+jr across the 16 lanes sharing g
    float mrow[4], lrow[4];
#pragma unroll
    for (int jr = 0; jr < 4; ++jr) {
      float m = -1e30f;
#pragma unroll
      for (int j = 0; j < 16; ++j)
        if (j <= t) m = fmaxf(m, s[j][jr]);
      m = fmaxf(m, __shfl_xor(m, 1));
      m = fmaxf(m, __shfl_xor(m, 2));
      m = fmaxf(m, __shfl_xor(m, 4));
      m = fmaxf(m, __shfl_xor(m, 8));
      mrow[jr] = m;
    }
#pragma unroll
    for (int jr = 0; jr < 4; ++jr) {
      float l = 0.0f;
#pragma unroll
      for (int j = 0; j < 16; ++j)
        if (j <= t) {
          float p = exp2f(s[j][jr] - mrow[jr]);
          s[j][jr] = p;
          l += p;
        }
      l += __shfl_xor(l, 1);
      l += __shfl_xor(l, 2);
      l += __shfl_xor(l, 4);
      l += __shfl_xor(l, 8);
      lrow[jr] = l;
    }

    // PV: per 32-token slice, transpose P through per-wave LDS buffer
    f32x4 o[4];
#pragma unroll
    for (int ct = 0; ct < 4; ++ct) o[ct] = zf;
#pragma unroll
    for (int ks = 0; ks < 8; ++ks) {
      if (2 * ks <= t) {
#pragma unroll
        for (int half = 0; half < 2; ++half) {
          int tile = 2 * ks + half;
          unsigned int p01 = 0, p23 = 0;
          if (tile <= t) {
            p01 = f2bf2(s[tile][0], s[tile][1]);
            p23 = f2bf2(s[tile][2], s[tile][3]);
          }
          Pb[(4 * g + 0) * 40 + half * 16 + q] = (unsigned short)p01;
          Pb[(4 * g + 1) * 40 + half * 16 + q] = (unsigned short)(p01 >> 16);
          Pb[(4 * g + 2) * 40 + half * 16 + q] = (unsigned short)p23;
          Pb[(4 * g + 3) * 40 + half * 16 + q] = (unsigned short)(p23 >> 16);
        }
        short8 ap = *(const short8*)&Pb[q * 40 + g * 8];
#pragma unroll
        for (int ct = 0; ct < 4; ++ct) {
          short8 bv = *(const short8*)&Vl[(16 * ct + q) * 264 + ks * 32 + g * 8];
          o[ct] = MFMA(ap, bv, o[ct]);
        }
      }
    }

    // epilogue: out fp32 [b][tok][h], fold in 1/rowsum
    const long rowbase = (long)b * 256 + 16 * t + 4 * g;
#pragma unroll
    for (int jr = 0; jr < 4; ++jr) {
      float inv = 1.0f / lrow[jr];
#pragma unroll
      for (int ct = 0; ct < 4; ++ct) {
        out[(rowbase + jr) * 64 + 16 * ct + q] = o[ct][jr] * inv;
      }
    }
  }
}

// ---------------------------------------------------------------------------
extern "C" void kernel_launch(void* const* d_in, const int* in_sizes, int n_in,
                              void* d_out, int out_size, void* d_ws, size_t ws_size,
                              hipStream_t stream) {
  const float* x  = (const float*)d_in[0];
  const float* Wq = (const float*)d_in[1];
  const float* Wk = (const float*)d_in[2];
  const float* Wv = (const float*)d_in[3];
  float* out = (float*)d_out;

  unsigned short* W3t = (unsigned short*)d_ws;  // 147,456 B

  hipFuncSetAttribute((const void*)fused_kernel,
                      hipFuncAttributeMaxDynamicSharedMemorySize, 117760);

  wconv_kernel<<<384, 192, 0, stream>>>(Wq, Wk, Wv, W3t);
  fused_kernel<<<256, 512, 117760, stream>>>(x, W3t, out);
}

// Round 4
// 40.148 us; speedup vs baseline: 1.2774x; 1.2774x over previous
//
#include <hip/hip_runtime.h>
#include <hip/hip_bf16.h>

typedef __attribute__((ext_vector_type(8))) short short8;
typedef __attribute__((ext_vector_type(4))) float f32x4;

#define MFMA(a, b, c) __builtin_amdgcn_mfma_f32_16x16x32_bf16((a), (b), (c), 0, 0, 0)

__device__ __forceinline__ unsigned short f2bf(float f) {
  union { float f; unsigned int u; } v; v.f = f;
  unsigned int u = v.u;
  unsigned int r = u + 0x7FFFu + ((u >> 16) & 1u);  // RNE
  return (unsigned short)(r >> 16);
}

// packed pair: low 16 = bf16(a), high 16 = bf16(b) -> v_cvt_pk_bf16_f32
__device__ __forceinline__ unsigned int f2bf2(float a, float b) {
  __hip_bfloat162 h2 = __float22bfloat162_rn(make_float2(a, b));
  union { __hip_bfloat162 h; unsigned int u; } cv; cv.h = h2;
  return cv.u;
}

// ---------------------------------------------------------------------------
// k0: W -> W3t bf16 [192 n][384 k] (transposed). Coalesced writes.
// ---------------------------------------------------------------------------
__global__ void wconv_kernel(const float* __restrict__ Wq, const float* __restrict__ Wk,
                             const float* __restrict__ Wv, unsigned short* __restrict__ W3t) {
  int n = blockIdx.x;   // 0..191
  int k = threadIdx.x;  // 0..383
  const float* src = (n < 64) ? Wq : ((n < 128) ? Wk : Wv);
  W3t[n * 384 + k] = f2bf(src[k * 64 + (n & 63)]);
}

// ---------------------------------------------------------------------------
// Fused per-batch kernel. 1024 threads = 16 waves (4/SIMD), 1 block/CU.
// Dynamic LDS 128,000 B (64,000 ush):
//   attn-phase: Ql [256][72] @0 | Kl [256][72] @18432 | Vl [64][264] @36864
//               Pb 16 x [16][40] @53760
//   proj-phase: stage buf0 @0, buf1 @17920 (each: xl 10240 + wl 7680 ush)
//               (overlays Ql/Kl -- written only in the epilogue)
// ---------------------------------------------------------------------------
__global__ __launch_bounds__(1024) void fused_kernel(
    const float* __restrict__ x, const unsigned short* __restrict__ W3t,
    float* __restrict__ out) {
  extern __shared__ unsigned short sm[];
  unsigned short* Ql = sm;
  unsigned short* Kl = sm + 18432;
  unsigned short* Vl = sm + 36864;

  const int tid = threadIdx.x;  // 0..1023
  const int w = tid >> 6, lane = tid & 63, g = lane >> 4, q = lane & 15;
  const int b = blockIdx.x;
  const float* xb = x + (long)b * 256 * 384;

  f32x4 acc[12];
  const f32x4 zf = {0.f, 0.f, 0.f, 0.f};
#pragma unroll
  for (int j = 0; j < 12; ++j) acc[j] = zf;

  // ---- staging: single register set, 1-deep prefetch ----
  // x: 2 float4/thread: i = tid + it*1024 -> row i>>3, col4 (i&7)*4
  // W: 1 uint4 for tid<768: n = tid>>2, koff = (tid&3)*8
  float4 xr0, xr1;
  uint4 wr1;
  const bool wact = (tid < 768);
  const int wn = tid >> 2, wk = (tid & 3) * 8;
  const int xrow0 = tid >> 3, xrow1 = (tid + 1024) >> 3, xc4 = (tid & 7) * 4;

  auto LOAD = [&](int k0) {
    xr0 = *(const float4*)&xb[xrow0 * 384 + k0 + xc4];
    xr1 = *(const float4*)&xb[xrow1 * 384 + k0 + xc4];
    if (wact) wr1 = *(const uint4*)&W3t[wn * 384 + k0 + wk];
  };
  auto WRITE = [&](int bufofs) {
    uint2 p0, p1;
    p0.x = f2bf2(xr0.x, xr0.y); p0.y = f2bf2(xr0.z, xr0.w);
    p1.x = f2bf2(xr1.x, xr1.y); p1.y = f2bf2(xr1.z, xr1.w);
    *(uint2*)&sm[bufofs + xrow0 * 40 + xc4] = p0;
    *(uint2*)&sm[bufofs + xrow1 * 40 + xc4] = p1;
    if (wact) *(uint4*)&sm[bufofs + 10240 + wn * 40 + wk] = wr1;
  };
  auto STEP = [&](int bufofs) {
    const unsigned short* xlb = sm + bufofs;
    const unsigned short* wlb = sm + bufofs + 10240;
    short8 a0 = *(const short8*)&xlb[(16 * w + q) * 40 + g * 8];
#pragma unroll
    for (int ct = 0; ct < 12; ++ct) {
      short8 bfr = *(const short8*)&wlb[(16 * ct + q) * 40 + g * 8];
      acc[ct] = MFMA(a0, bfr, acc[ct]);
    }
  };

  LOAD(0);
#pragma unroll
  for (int s = 0; s < 12; ++s) {
    const int bo = (s & 1) ? 17920 : 0;
    WRITE(bo);                    // waits on this step's loads (vmcnt)
    if (s < 11) LOAD(32 * (s + 1));
    __syncthreads();              // buf[bo] complete for all waves
    STEP(bo);                     // overlaps next wave's WRITE to other buf
  }
  __syncthreads();  // stage buffers dead; epilogue may overwrite Ql/Kl

  // ---- proj epilogue: QKV -> LDS (D layout: col=lane&15, row=4g+reg) ----
  {
    const int mb = 16 * w + 4 * g;  // within-batch row base
#pragma unroll
    for (int ct = 0; ct < 12; ++ct) {
      int c = 16 * ct + q;
      unsigned int p01 = f2bf2(acc[ct][0], acc[ct][1]);
      unsigned int p23 = f2bf2(acc[ct][2], acc[ct][3]);
      unsigned short h0 = (unsigned short)p01, h1 = (unsigned short)(p01 >> 16);
      unsigned short h2 = (unsigned short)p23, h3 = (unsigned short)(p23 >> 16);
      if (ct < 4) {
        Ql[(mb + 0) * 72 + c] = h0; Ql[(mb + 1) * 72 + c] = h1;
        Ql[(mb + 2) * 72 + c] = h2; Ql[(mb + 3) * 72 + c] = h3;
      } else if (ct < 8) {
        int cc = c - 64;
        Kl[(mb + 0) * 72 + cc] = h0; Kl[(mb + 1) * 72 + cc] = h1;
        Kl[(mb + 2) * 72 + cc] = h2; Kl[(mb + 3) * 72 + cc] = h3;
      } else {
        int hh = c - 128;
        uint2 pk; pk.x = p01; pk.y = p23;
        *(uint2*)&Vl[hh * 264 + mb] = pk;  // V^T[h][tok..tok+3]
      }
    }
  }
  __syncthreads();

  // ---- attention: wave w owns row-tile t = w; online (flash) softmax ----
  unsigned short* Pb = sm + 53760 + w * 640;  // per-wave [16][40] xpose buf
  const float SCL = 0.125f * 1.4426950408889634f;  // H^-0.5 * log2(e)
  const int t = w;

  short8 aq0 = *(const short8*)&Ql[(16 * t + q) * 72 + g * 8];
  short8 aq1 = *(const short8*)&Ql[(16 * t + q) * 72 + 32 + g * 8];

  f32x4 o[4];
#pragma unroll
  for (int ct = 0; ct < 4; ++ct) o[ct] = zf;
  float mrow[4] = {-1e30f, -1e30f, -1e30f, -1e30f};
  float lrow[4] = {0.f, 0.f, 0.f, 0.f};

#pragma unroll
  for (int ks = 0; ks < 8; ++ks) {
    if (2 * ks <= t) {
      const int j0 = 2 * ks, j1 = 2 * ks + 1;
      const bool has1 = (j1 <= t);
      // QK^T for the two 16-col tiles
      short8 bk0a = *(const short8*)&Kl[(16 * j0 + q) * 72 + g * 8];
      short8 bk0b = *(const short8*)&Kl[(16 * j0 + q) * 72 + 32 + g * 8];
      f32x4 s0 = MFMA(aq0, bk0a, zf);
      s0 = MFMA(aq1, bk0b, s0);
      f32x4 s1;
      if (has1) {
        short8 bk1a = *(const short8*)&Kl[(16 * j1 + q) * 72 + g * 8];
        short8 bk1b = *(const short8*)&Kl[(16 * j1 + q) * 72 + 32 + g * 8];
        s1 = MFMA(aq0, bk1a, zf);
        s1 = MFMA(aq1, bk1b, s1);
      }
      float p0[4], p1[4];
#pragma unroll
      for (int jr = 0; jr < 4; ++jr) {
        float v0 = s0[jr] * SCL;
        if (j0 == t && q > 4 * g + jr) v0 = -1e30f;  // causal (diag tile)
        float v1 = -1e30f;
        if (has1) {
          v1 = s1[jr] * SCL;
          if (j1 == t && q > 4 * g + jr) v1 = -1e30f;
        }
        // running max over this row (16 q-lanes share row 16t+4g+jr)
        float loc = fmaxf(v0, v1);
        loc = fmaxf(loc, __shfl_xor(loc, 1));
        loc = fmaxf(loc, __shfl_xor(loc, 2));
        loc = fmaxf(loc, __shfl_xor(loc, 4));
        loc = fmaxf(loc, __shfl_xor(loc, 8));
        float mnew = fmaxf(mrow[jr], loc);
        float f = exp2f(mrow[jr] - mnew);   // first iter: exp2(-inf) = 0
        mrow[jr] = mnew;
        p0[jr] = exp2f(v0 - mnew);
        p1[jr] = exp2f(v1 - mnew);
        lrow[jr] = lrow[jr] * f + p0[jr] + p1[jr];
        o[0][jr] *= f; o[1][jr] *= f; o[2][jr] *= f; o[3][jr] *= f;
      }
      // write P (both tiles) to per-wave buffer, read back transposed
      unsigned int a01 = f2bf2(p0[0], p0[1]), a23 = f2bf2(p0[2], p0[3]);
      unsigned int b01 = f2bf2(p1[0], p1[1]), b23 = f2bf2(p1[2], p1[3]);
      Pb[(4 * g + 0) * 40 + q]      = (unsigned short)a01;
      Pb[(4 * g + 1) * 40 + q]      = (unsigned short)(a01 >> 16);
      Pb[(4 * g + 2) * 40 + q]      = (unsigned short)a23;
      Pb[(4 * g + 3) * 40 + q]      = (unsigned short)(a23 >> 16);
      Pb[(4 * g + 0) * 40 + 16 + q] = (unsigned short)b01;
      Pb[(4 * g + 1) * 40 + 16 + q] = (unsigned short)(b01 >> 16);
      Pb[(4 * g + 2) * 40 + 16 + q] = (unsigned short)b23;
      Pb[(4 * g + 3) * 40 + 16 + q] = (unsigned short)(b23 >> 16);
      short8 ap = *(const short8*)&Pb[q * 40 + g * 8];
#pragma unroll
      for (int ct = 0; ct < 4; ++ct) {
        short8 bv = *(const short8*)&Vl[(16 * ct + q) * 264 + ks * 32 + g * 8];
        o[ct] = MFMA(ap, bv, o[ct]);
      }
    }
  }

  // final row-sum reduce + store
  const long rowbase = (long)b * 256 + 16 * t + 4 * g;
#pragma unroll
  for (int jr = 0; jr < 4; ++jr) {
    float l = lrow[jr];
    l += __shfl_xor(l, 1);
    l += __shfl_xor(l, 2);
    l += __shfl_xor(l, 4);
    l += __shfl_xor(l, 8);
    float inv = 1.0f / l;
#pragma unroll
    for (int ct = 0; ct < 4; ++ct) {
      out[(rowbase + jr) * 64 + 16 * ct + q] = o[ct][jr] * inv;
    }
  }
}

// ---------------------------------------------------------------------------
extern "C" void kernel_launch(void* const* d_in, const int* in_sizes, int n_in,
                              void* d_out, int out_size, void* d_ws, size_t ws_size,
                              hipStream_t stream) {
  const float* x  = (const float*)d_in[0];
  const float* Wq = (const float*)d_in[1];
  const float* Wk = (const float*)d_in[2];
  const float* Wv = (const float*)d_in[3];
  float* out = (float*)d_out;

  unsigned short* W3t = (unsigned short*)d_ws;  // 147,456 B

  hipFuncSetAttribute((const void*)fused_kernel,
                      hipFuncAttributeMaxDynamicSharedMemorySize, 128000);

  wconv_kernel<<<192, 384, 0, stream>>>(Wq, Wk, Wv, W3t);
  fused_kernel<<<256, 1024, 128000, stream>>>(x, W3t, out);
}

// Round 6
// 36.952 us; speedup vs baseline: 1.3879x; 1.0865x over previous
//
#include <hip/hip_runtime.h>
#include <hip/hip_bf16.h>

typedef __attribute__((ext_vector_type(8))) short short8;
typedef __attribute__((ext_vector_type(4))) float f32x4;

#define MFMA(a, b, c) __builtin_amdgcn_mfma_f32_16x16x32_bf16((a), (b), (c), 0, 0, 0)

// packed pair: low 16 = bf16(a), high 16 = bf16(b) -> v_cvt_pk_bf16_f32
__device__ __forceinline__ unsigned int f2bf2(float a, float b) {
  __hip_bfloat162 h2 = __float22bfloat162_rn(make_float2(a, b));
  union { __hip_bfloat162 h; unsigned int u; } cv; cv.h = h2;
  return cv.u;
}

// ---------------------------------------------------------------------------
// k0: W -> W3t bf16 in FRAG-LINEAR layout: 16B chunk index
//   j = (kstep*12 + ct)*64 + lane,  lane=(g*16+q)
// holding W^T[n=16ct'+q][k=32*kstep+8g .. +7]  (ct': Q ct 0-3, K 4-7, V 8-11)
// so fused's B-frag ds_read_b128 is lane-unit-stride (conflict-free).
// ---------------------------------------------------------------------------
__global__ void wconv_kernel(const float* __restrict__ Wq, const float* __restrict__ Wk,
                             const float* __restrict__ Wv, unsigned short* __restrict__ W3t) {
  int j = blockIdx.x * 256 + threadIdx.x;  // 0..9215 (uint4 chunks)
  int s = j / 768;
  int r = j - s * 768;
  int ct = r >> 6, l = r & 63, g = l >> 4, q = l & 15;
  const float* src = (ct < 4) ? Wq : ((ct < 8) ? Wk : Wv);
  int col = 16 * (ct & 3) + q;
  int k = 32 * s + 8 * g;
  float e[8];
#pragma unroll
  for (int i = 0; i < 8; ++i) e[i] = src[(k + i) * 64 + col];
  uint4 u;
  u.x = f2bf2(e[0], e[1]); u.y = f2bf2(e[2], e[3]);
  u.z = f2bf2(e[4], e[5]); u.w = f2bf2(e[6], e[7]);
  *(uint4*)&W3t[j * 8] = u;
}

// ---------------------------------------------------------------------------
// Fused per-batch kernel. 1024 threads = 16 waves (4/SIMD), 1 block/CU.
// Dynamic LDS 147456 B (73728 ush):
//   proj-phase: Wf frag-linear, whole W (9216 x 16B chunks)
//   attn-phase (overlays Wf): Ql [256][72] @0 | Kl @18432 | Vl [64][264] @36864
//                             Pb 16 x [16][40] @53760 (ends 64000 ush)
// Proj: NO main-loop barriers. x: direct global->reg A-frags (1-step prefetch).
// Attn: swapped QK^T (scores lane-local per q-row), online softmax, tile t=w.
// Per-row factors are redistributed to accumulator rows via __shfl (the
// PV accumulator's D-row is 4g+jr, while f/lsum live at lane q=row).
// ---------------------------------------------------------------------------
__global__ __launch_bounds__(1024) void fused_kernel(
    const float* __restrict__ x, const unsigned short* __restrict__ W3t,
    float* __restrict__ out) {
  extern __shared__ unsigned short sm[];
  unsigned short* Ql = sm;
  unsigned short* Kl = sm + 18432;
  unsigned short* Vl = sm + 36864;

  const int tid = threadIdx.x;  // 0..1023
  const int w = tid >> 6, lane = tid & 63, g = lane >> 4, q = lane & 15;
  const int b = blockIdx.x;
  const float* xb = x + (long)b * 98304;

  // ---- stage whole W into LDS (frag-linear; coalesced; conflict-free) ----
#pragma unroll
  for (int i = 0; i < 9; ++i) {
    int idx = tid + i * 1024;  // uint4 chunk index
    *(uint4*)&sm[idx * 8] = *(const uint4*)&W3t[idx * 8];
  }

  f32x4 acc[12];
  const f32x4 zf = {0.f, 0.f, 0.f, 0.f};
#pragma unroll
  for (int j = 0; j < 12; ++j) acc[j] = zf;

  // x A-frag source: lane (q,g) owns row 16w+q, k-chunk 8g..8g+7 (+32s)
  const float* xrow = xb + (16 * w + q) * 384 + 8 * g;
  float4 x0 = *(const float4*)&xrow[0];
  float4 x1 = *(const float4*)&xrow[4];

  __syncthreads();  // Wf staged (x0/x1 loads already in flight)

  // ---- proj main loop: free-running, no barriers ----
#pragma unroll
  for (int ks = 0; ks < 12; ++ks) {
    float4 n0, n1;
    if (ks < 11) {
      n0 = *(const float4*)&xrow[32 * (ks + 1)];
      n1 = *(const float4*)&xrow[32 * (ks + 1) + 4];
    }
    uint4 au;
    au.x = f2bf2(x0.x, x0.y); au.y = f2bf2(x0.z, x0.w);
    au.z = f2bf2(x1.x, x1.y); au.w = f2bf2(x1.z, x1.w);
    union { uint4 u; short8 s8; } av; av.u = au;
    const unsigned short* wbase = sm + ks * 6144 + lane * 8;
#pragma unroll
    for (int ct = 0; ct < 12; ++ct) {
      short8 bfr = *(const short8*)&wbase[ct * 512];
      acc[ct] = MFMA(av.s8, bfr, acc[ct]);
    }
    if (ks < 11) { x0 = n0; x1 = n1; }
  }
  __syncthreads();  // all waves done reading Wf; safe to overlay

  // ---- proj epilogue: QKV -> LDS (D layout: col=lane&15, row=4g+reg) ----
  {
    const int mb = 16 * w + 4 * g;  // within-batch row base
#pragma unroll
    for (int ct = 0; ct < 12; ++ct) {
      int c = 16 * ct + q;
      unsigned int p01 = f2bf2(acc[ct][0], acc[ct][1]);
      unsigned int p23 = f2bf2(acc[ct][2], acc[ct][3]);
      unsigned short h0 = (unsigned short)p01, h1 = (unsigned short)(p01 >> 16);
      unsigned short h2 = (unsigned short)p23, h3 = (unsigned short)(p23 >> 16);
      if (ct < 4) {
        Ql[(mb + 0) * 72 + c] = h0; Ql[(mb + 1) * 72 + c] = h1;
        Ql[(mb + 2) * 72 + c] = h2; Ql[(mb + 3) * 72 + c] = h3;
      } else if (ct < 8) {
        int cc = c - 64;
        Kl[(mb + 0) * 72 + cc] = h0; Kl[(mb + 1) * 72 + cc] = h1;
        Kl[(mb + 2) * 72 + cc] = h2; Kl[(mb + 3) * 72 + cc] = h3;
      } else {
        int hh = c - 128;
        uint2 pk; pk.x = p01; pk.y = p23;
        *(uint2*)&Vl[hh * 264 + mb] = pk;  // V^T[h][tok..tok+3]
      }
    }
  }
  __syncthreads();

  // ---- attention: wave w owns row-tile t = w; swapped QK^T + online SM ----
  unsigned short* Pb = sm + 53760 + w * 640;  // per-wave [16][40] P buffer
  const float SCL = 0.125f * 1.4426950408889634f;  // H^-0.5 * log2(e)
  const int t = w;

  // Q as B-operand: lane (q,g) holds Q[16t+q][8g..8g+7]
  short8 aq0 = *(const short8*)&Ql[(16 * t + q) * 72 + g * 8];
  short8 aq1 = *(const short8*)&Ql[(16 * t + q) * 72 + 32 + g * 8];

  f32x4 o[4];
#pragma unroll
  for (int ct = 0; ct < 4; ++ct) o[ct] = zf;
  float m = -1e30f;   // running max for q-row 16t+q (uniform across g after reduce)
  float lsum = 0.f;   // per-lane partial row-sum for q-row 16t+q

  const int KS = (t >> 1) + 1;  // runtime trip count, wave-uniform
  for (int ks = 0; ks < KS; ++ks) {
    const int j0 = 2 * ks, j1 = 2 * ks + 1;
    const bool has1 = (j1 <= t);
    // K as A-operand: D[row=4g+jr][col=q] = S[K-token 16j+4g+jr][Q-row 16t+q]
    //   -> scores for THIS lane's q-row are lane-local (v[jr])
    short8 ka0 = *(const short8*)&Kl[(16 * j0 + q) * 72 + g * 8];
    short8 ka1 = *(const short8*)&Kl[(16 * j0 + q) * 72 + 32 + g * 8];
    f32x4 s0 = MFMA(ka0, aq0, zf);
    s0 = MFMA(ka1, aq1, s0);
    f32x4 s1 = zf;
    if (has1) {
      short8 kb0 = *(const short8*)&Kl[(16 * j1 + q) * 72 + g * 8];
      short8 kb1 = *(const short8*)&Kl[(16 * j1 + q) * 72 + 32 + g * 8];
      s1 = MFMA(kb0, aq0, zf);
      s1 = MFMA(kb1, aq1, s1);
    }
    float v[8];
#pragma unroll
    for (int jr = 0; jr < 4; ++jr) {
      float a = s0[jr] * SCL;
      if (j0 == t && 4 * g + jr > q) a = -1e30f;  // causal (diag tile)
      v[jr] = a;
      float c = has1 ? s1[jr] * SCL : -1e30f;
      if (has1 && j1 == t && 4 * g + jr > q) c = -1e30f;
      v[4 + jr] = c;
    }
    float mloc = fmaxf(fmaxf(fmaxf(v[0], v[1]), fmaxf(v[2], v[3])),
                       fmaxf(fmaxf(v[4], v[5]), fmaxf(v[6], v[7])));
    mloc = fmaxf(mloc, __shfl_xor(mloc, 16));
    mloc = fmaxf(mloc, __shfl_xor(mloc, 32));
    float mnew = fmaxf(m, mloc);
    float f = exp2f(m - mnew);  // rescale factor for q-row q (this lane's row)
    m = mnew;
    float p[8];
    float ls = 0.f;
#pragma unroll
    for (int i = 0; i < 8; ++i) { p[i] = exp2f(v[i] - mnew); ls += p[i]; }
    lsum = lsum * f + ls;
    // o[ct][jr] is the accumulator for Q-row 4g+jr -> fetch THAT row's factor
    // (held by lane with q' = 4g+jr; lane index 4g+jr has q'=4g+jr, g'=0)
#pragma unroll
    for (int jr = 0; jr < 4; ++jr) {
      float fr = __shfl(f, 4 * g + jr);
      o[0][jr] *= fr; o[1][jr] *= fr; o[2][jr] *= fr; o[3][jr] *= fr;
    }
    // P store (row q, cols 4g..4g+3 of each 16-tile) then transposed read
    uint2 pa; pa.x = f2bf2(p[0], p[1]); pa.y = f2bf2(p[2], p[3]);
    *(uint2*)&Pb[q * 40 + 4 * g] = pa;
    uint2 pc; pc.x = f2bf2(p[4], p[5]); pc.y = f2bf2(p[6], p[7]);
    *(uint2*)&Pb[q * 40 + 16 + 4 * g] = pc;
    short8 ap = *(const short8*)&Pb[q * 40 + g * 8];
#pragma unroll
    for (int ct = 0; ct < 4; ++ct) {
      short8 bv = *(const short8*)&Vl[(16 * ct + q) * 264 + ks * 32 + g * 8];
      o[ct] = MFMA(ap, bv, o[ct]);
    }
  }

  // final row-sum: fold g-partials (row q), then fetch row 4g+jr's sum
  lsum += __shfl_xor(lsum, 16);
  lsum += __shfl_xor(lsum, 32);
  float linv[4];
#pragma unroll
  for (int jr = 0; jr < 4; ++jr) linv[jr] = 1.0f / __shfl(lsum, 4 * g + jr);

  const long rowbase = (long)b * 256 + 16 * t;
#pragma unroll
  for (int jr = 0; jr < 4; ++jr) {
#pragma unroll
    for (int ct = 0; ct < 4; ++ct) {
      out[(rowbase + 4 * g + jr) * 64 + 16 * ct + q] = o[ct][jr] * linv[jr];
    }
  }
}

// ---------------------------------------------------------------------------
extern "C" void kernel_launch(void* const* d_in, const int* in_sizes, int n_in,
                              void* d_out, int out_size, void* d_ws, size_t ws_size,
                              hipStream_t stream) {
  const float* x  = (const float*)d_in[0];
  const float* Wq = (const float*)d_in[1];
  const float* Wk = (const float*)d_in[2];
  const float* Wv = (const float*)d_in[3];
  float* out = (float*)d_out;

  unsigned short* W3t = (unsigned short*)d_ws;  // 147,456 B

  hipFuncSetAttribute((const void*)fused_kernel,
                      hipFuncAttributeMaxDynamicSharedMemorySize, 147456);

  wconv_kernel<<<36, 256, 0, stream>>>(Wq, Wk, Wv, W3t);
  fused_kernel<<<256, 1024, 147456, stream>>>(x, W3t, out);
}